// Round 5
// baseline (483.605 us; speedup 1.0000x reference)
//
#include <hip/hip_runtime.h>
#include <cstdint>
#include <cstddef>

// Problem constants: P=2048, K=8, T=32, C=16384, F=128
#define PP 2048
#define KK 8
#define TT 32
#define FF 128
#define MB 8
#define NBLK (PP/MB)    // 256 blocks -> 1 block/CU on 256 CUs
#define NTHR 512
#define NSTEP (KK*TT)   // 256
#define NMAC (NSTEP/4)  // 64 macros of 4 steps

typedef __attribute__((ext_vector_type(8))) short short8;  // 8 bf16 (4 VGPRs)
typedef __attribute__((ext_vector_type(4))) float f32x4;   // MFMA C/D frag

__device__ __forceinline__ uint32_t fbits(float x){ union{float f;uint32_t u;}c;c.f=x;return c.u; }
__device__ __forceinline__ uint32_t rne16(uint32_t u){
    return (u + 0x7fffu + ((u >> 16) & 1u)) >> 16;
}
__device__ __forceinline__ short bf_rne(float x){ return (short)rne16(fbits(x)); }
// HW packed f32->bf16 RNE: 1 instr (gfx950, no builtin)
__device__ __forceinline__ uint32_t cvtpk(float a, float b){
    uint32_t r;
    asm("v_cvt_pk_bf16_f32 %0, %1, %2" : "=v"(r) : "v"(a), "v"(b));
    return r;
}
__device__ __forceinline__ float sigm(float x){
    float t = __expf(-x);                    // x->-inf: t=inf -> rcp=0; x->inf: t=0 -> 1
    return __builtin_amdgcn_rcpf(1.f + t);
}
__device__ __forceinline__ float tanh_fast(float x){
    float e = __expf(-2.f * x);              // saturates correctly via inf -> rcp -> 0
    return __builtin_amdgcn_rcpf(1.f + e) * 2.f - 1.f;
}

#define MF(a,b,c) __builtin_amdgcn_mfma_f32_16x16x32_bf16(a,b,c,0,0,0)

// Block: 8 paths x 256 steps as TWO INDEPENDENT 4-path GRU chains (A=paths
// 0..3, B=paths 4..7) running ANTIPHASE in one instruction stream, sharing
// one 96-VGPR weight set. 256 blocks -> all CUs, 1 block/CU, VGPR cap 256
// (launch_bounds(512,2)) -> no spill risk (the R4 2-block/CU design could
// not fit 128).
//
// Interval i (one barrier): phase1 = B-gates(step i-1) from held tB regs +
// write h_B frags; BARRIER; phase2 = A reads h_A + 12 h-MFMA + gates(i) +
// write h_A, while B reads h_B + 12 h-MFMA -> tB held to next interval.
// B's MFMAs are the independent fill under A's serial ds_read->MFMA->
// transcendental chain and vice versa; trailing barrier dropped (all
// cross-phase LDS accesses in disjoint parities/rings).
//
// Per chain: R4's 4-dup row map (rows 4g..4g+3 = path g): every C-reg of
// lane (q,nl) = (path q, col 16w+nl) -> 1-row gate math, x-gate accumulator
// as h-MFMA C-in (bias-folded, reg j = step j, static via 4x unroll).
// dense-x: rows = 4 paths x 4 steps (step=row&3) -> 12 MFMAs per 4 steps
// per chain, refilled at j==3. x-ring (8 deep per chain): slot XORed with
// (ring&3) so the per-lane ring=nl&3 dense reads are bank-conflict-free.
// Stagers (waves 0-3) write step i+6, prefetch i+7; one barrier per step.
__global__ __launch_bounds__(NTHR, 2) void gru_mfma8(
    const float* __restrict__ h0,    // [P, F]
    const float* __restrict__ feat,  // [C, T, F]
    const float* __restrict__ w_ih,  // [3F, F]
    const float* __restrict__ w_hh,  // [3F, F]
    const float* __restrict__ b_ih,  // [3F]
    const float* __restrict__ b_hh,  // [3F]
    const int* __restrict__ idx,     // [P, K]
    float* __restrict__ out)         // [P, F]
{
    const int tid  = threadIdx.x;
    const int w    = tid >> 6;
    const int lane = tid & 63;
    const int q    = lane >> 4;
    const int nl   = lane & 15;
    const int p0   = blockIdx.x * MB;

    __shared__ __align__(16) short hAf[2][4][16][8];  // h frags chain A (2KB)
    __shared__ __align__(16) short hBf[2][4][16][8];  // h frags chain B (2KB)
    __shared__ __align__(16) short xAf[8][4][16][8];  // x ring chain A (8KB)
    __shared__ __align__(16) short xBf[8][4][16][8];  // x ring chain B (8KB)
    __shared__ int cix[MB][KK];

    // ---- B-fragments (weights, RNE bf16) resident in VGPRs (96), shared A/B
    short8 wbi[3][4], wbh[3][4];
#pragma unroll
    for (int tt = 0; tt < 3; ++tt) {
        const int g = (w + 8 * tt) * 16 + nl;
#pragma unroll
        for (int c = 0; c < 4; ++c) {
            const float* wi = w_ih + (size_t)g * FF + c * 32 + q * 8;
            const float* wh = w_hh + (size_t)g * FF + c * 32 + q * 8;
            short8 a, b;
#pragma unroll
            for (int j = 0; j < 8; ++j) { a[j] = bf_rne(wi[j]); b[j] = bf_rne(wh[j]); }
            wbi[tt][c] = a; wbh[tt][c] = b;
        }
    }
    const int fcol = w * 16 + nl;
    const float bR  = b_ih[fcol] + b_hh[fcol];
    const float bZ  = b_ih[FF + fcol] + b_hh[FF + fcol];
    const float bNi = b_ih[2 * FF + fcol];
    const float bNh = b_hh[2 * FF + fcol];
    const f32x4 bNh4 = {bNh, bNh, bNh, bNh};

    if (tid < MB * KK) cix[tid >> 3][tid & 7] = idx[(p0 + (tid >> 3)) * KK + (tid & 7)];

    // ---- producer: lane owns (path q, col fcol) in each chain
    const int qqF = (fcol >> 3) & 3;
    const int jF  = fcol & 7;
    const int cF  = w >> 1;
    short* hwA = &hAf[0][cF][q + 4 * qqF][jF];   // + par*512 shorts
    short* hwB = &hBf[0][cF][q + 4 * qqF][jF];

    // ---- consumer frag bases: slot = path(=nl>>2) + 4*qq(=q)
    const int slotC = (nl >> 2) + 4 * q;
    const short* hrA = &hAf[0][0][slotC][0];     // + par*512 + c*128
    const short* hrB = &hBf[0][0][slotC][0];
    const int st4   = nl & 3;                    // dense: lane's step-in-macro
    const int xslot = slotC ^ st4;               // ring-aware XOR swizzle
    const short* xrA = &xAf[0][0][xslot][0];     // + (base+st4)*512 + c*128
    const short* xrB = &xBf[0][0][xslot][0];

    // ---- h0 masters + initial frags (parity 0)
    float hmA = h0[(size_t)(p0 + q)     * FF + fcol];
    float hmB = h0[(size_t)(p0 + 4 + q) * FF + fcol];
    hwA[0] = (short)cvtpk(hmA, hmA);
    hwB[0] = (short)cvtpk(hmB, hmB);

    // ---- stager mapping (waves 0-3): thread = (path_s, 4-float k chunk)
    const bool stg    = tid < 256;
    const int  path_s = tid >> 5;                // 0..7 for stagers
    const int  pg_s   = path_s & 3;
    const int  k16    = tid & 31;
    const int  k0s    = 4 * k16;
    const int  slot_s = pg_s + 4 * ((k16 >> 1) & 3);
    short* xwbase = (path_s < 4) ? &xAf[0][k16 >> 3][0][4 * (k16 & 1)]
                                 : &xBf[0][k16 >> 3][0][4 * (k16 & 1)];

    __syncthreads();  // B0: cix + h0 frags ready

    // ---- prologue: stage steps 0..5 into rings 0..5; prefetch step 6
    float4 xp;
    if (stg) {
        const int ch = cix[path_s][0];
        const float* base = feat + (size_t)ch * (TT * FF) + k0s;
#pragma unroll
        for (int s = 0; s < 6; ++s) {
            const float4 v = *(const float4*)(base + s * FF);
            uint2 a = { cvtpk(v.x, v.y), cvtpk(v.z, v.w) };
            *(uint2*)(xwbase + s * 512 + (slot_s ^ (s & 3)) * 8) = a;
        }
        xp = *(const float4*)(base + 6 * FF);
    }
    __syncthreads();  // B1: rings 0..5 staged

    // ---- prologue dense-x: x-gates for steps 0..3, both chains
    f32x4 xgAR, xgAZ, xgAN, xgBR, xgBZ, xgBN;
#define DENSE(gR, gZ, gN, ptr)  {                                             \
        const short8 a0 = *(const short8*)(ptr);                              \
        const short8 a1 = *(const short8*)((ptr) + 128);                      \
        const short8 a2 = *(const short8*)((ptr) + 256);                      \
        const short8 a3 = *(const short8*)((ptr) + 384);                      \
        f32x4 cR = {bR,bR,bR,bR}, cZ = {bZ,bZ,bZ,bZ}, cN = {bNi,bNi,bNi,bNi}; \
        cR = MF(a0,wbi[0][0],cR); cR = MF(a1,wbi[0][1],cR);                   \
        cR = MF(a2,wbi[0][2],cR); cR = MF(a3,wbi[0][3],cR);                   \
        cZ = MF(a0,wbi[1][0],cZ); cZ = MF(a1,wbi[1][1],cZ);                   \
        cZ = MF(a2,wbi[1][2],cZ); cZ = MF(a3,wbi[1][3],cZ);                   \
        cN = MF(a0,wbi[2][0],cN); cN = MF(a1,wbi[2][1],cN);                   \
        cN = MF(a2,wbi[2][2],cN); cN = MF(a3,wbi[2][3],cN);                   \
        gR = cR; gZ = cZ; gN = cN; }
    DENSE(xgAR, xgAZ, xgAN, xrA + st4 * 512)
    DENSE(xgBR, xgBZ, xgBN, xrB + st4 * 512)
    // (rings 0..3 first overwritten at interval 2 phase1 — 2 barriers away)

    f32x4 tBR, tBZ, tBN;
    float xnBsav = 0.f;

    for (int m = 0; m < NMAC; ++m) {
#pragma unroll
        for (int j = 0; j < 4; ++j) {
            const int i = 4 * m + j;

            // ---- phase 1: B-gates for step i-1 (tB held from prev interval)
            if (j > 0 || m > 0) {
                const int jj = (j + 3) & 3;                  // static
                const float xnB = (j == 0) ? xnBsav : xgBN[jj];
                const float rg  = sigm(tBR[jj]);
                const float zg  = sigm(tBZ[jj]);
                const float np_ = xnB + rg * tBN[jj];
                const float ng  = tanh_fast(np_);
                hmB = ng + zg * (hmB - ng);
                hwB[(j & 1) * 512] = (short)cvtpk(hmB, hmB);  // par = i&1
            }
            // ---- phase 1: stager (write step i+6, prefetch i+7)
            if (stg) {
                const int s6 = i + 6;
                if (s6 < NSTEP) {
                    uint2 a = { cvtpk(xp.x, xp.y), cvtpk(xp.z, xp.w) };
                    *(uint2*)(xwbase + (s6 & 7) * 512 + (slot_s ^ (s6 & 3)) * 8) = a;
                }
                const int s7 = i + 7;
                if (s7 < NSTEP) {
                    const int ch = cix[path_s][s7 >> 5];
                    xp = *(const float4*)(feat + (size_t)ch * (TT * FF) + (s7 & 31) * FF + k0s);
                }
            }
            __syncthreads();  // the ONE barrier per step

            // ---- phase 2: chain A (critical) + chain B (fill)
            const short* ha = hrA + (j & 1) * 512;           // par = i&1
            const short* hb = hrB + (j & 1) * 512;
            const short8 hA0 = *(const short8*)(ha);
            const short8 hA1 = *(const short8*)(ha + 128);
            const short8 hA2 = *(const short8*)(ha + 256);
            const short8 hA3 = *(const short8*)(ha + 384);

            f32x4 tAR = MF(hA0, wbh[0][0], xgAR);
            tAR = MF(hA1, wbh[0][1], tAR);
            tAR = MF(hA2, wbh[0][2], tAR);
            tAR = MF(hA3, wbh[0][3], tAR);
            f32x4 tAZ = MF(hA0, wbh[1][0], xgAZ);
            tAZ = MF(hA1, wbh[1][1], tAZ);
            tAZ = MF(hA2, wbh[1][2], tAZ);
            tAZ = MF(hA3, wbh[1][3], tAZ);
            f32x4 tAN = MF(hA0, wbh[2][0], bNh4);
            tAN = MF(hA1, wbh[2][1], tAN);
            tAN = MF(hA2, wbh[2][2], tAN);
            tAN = MF(hA3, wbh[2][3], tAN);

            const short8 hB0 = *(const short8*)(hb);
            const short8 hB1 = *(const short8*)(hb + 128);
            const short8 hB2 = *(const short8*)(hb + 256);
            const short8 hB3 = *(const short8*)(hb + 384);
            tBR = MF(hB0, wbh[0][0], xgBR);
            tBR = MF(hB1, wbh[0][1], tBR);
            tBR = MF(hB2, wbh[0][2], tBR);
            tBR = MF(hB3, wbh[0][3], tBR);
            tBZ = MF(hB0, wbh[1][0], xgBZ);
            tBZ = MF(hB1, wbh[1][1], tBZ);
            tBZ = MF(hB2, wbh[1][2], tBZ);
            tBZ = MF(hB3, wbh[1][3], tBZ);
            tBN = MF(hB0, wbh[2][0], bNh4);
            tBN = MF(hB1, wbh[2][1], tBN);
            tBN = MF(hB2, wbh[2][2], tBN);
            tBN = MF(hB3, wbh[2][3], tBN);

            // ---- A gates (step i, static reg j)
            {
                const float rg  = sigm(tAR[j]);
                const float zg  = sigm(tAZ[j]);
                const float np_ = xgAN[j] + rg * tAN[j];
                const float ng  = tanh_fast(np_);
                hmA = ng + zg * (hmA - ng);
                hwA[((j & 1) ^ 1) * 512] = (short)cvtpk(hmA, hmA);
            }

            // ---- dense-x refill for next macro (steps 4m+4..4m+7)
            if (j == 3 && m < NMAC - 1) {
                xnBsav = xgBN[3];                 // consumed at next phase1
                const int rb = 4 * ((m + 1) & 1);
                DENSE(xgAR, xgAZ, xgAN, xrA + (rb + st4) * 512)
                DENSE(xgBR, xgBZ, xgBN, xrB + (rb + st4) * 512)
            }
            // no trailing barrier: next phase1 touches only disjoint
            // parities/rings; next phase2 reads are behind the next barrier
        }
    }

    // ---- epilogue: B step 255 gates (tB from last interval, xg intact)
    {
        const float rg  = sigm(tBR[3]);
        const float zg  = sigm(tBZ[3]);
        const float np_ = xgBN[3] + rg * tBN[3];
        const float ng  = tanh_fast(np_);
        hmB = ng + zg * (hmB - ng);
    }
    out[(size_t)(p0 + q)     * FF + fcol] = hmA;
    out[(size_t)(p0 + 4 + q) * FF + fcol] = hmB;
}

extern "C" void kernel_launch(void* const* d_in, const int* in_sizes, int n_in,
                              void* d_out, int out_size, void* d_ws, size_t ws_size,
                              hipStream_t stream) {
    const float* h0   = (const float*)d_in[0];
    const float* feat = (const float*)d_in[1];
    const float* wih  = (const float*)d_in[2];
    const float* whh  = (const float*)d_in[3];
    const float* bih  = (const float*)d_in[4];
    const float* bhh  = (const float*)d_in[5];
    const int*   idx  = (const int*)d_in[6];
    float*       out  = (float*)d_out;

    gru_mfma8<<<dim3(NBLK), dim3(NTHR), 0, stream>>>(
        h0, feat, wih, whh, bih, bhh, idx, out);
}